// Round 1
// baseline (329.555 us; speedup 1.0000x reference)
//
#include <hip/hip_runtime.h>

#define N_PTS 20000
#define CIN   32
#define COUT  64
#define KK    4
#define KF    64            // 4*4*4
#define E_PAD 262144
#define EPS   1e-12f
#define FOUR_OVER_PI 1.27323954473516f
#define QB    8             // queries per block

__device__ __forceinline__ float sgnf(float v) {
    return v > 0.f ? 1.f : (v < 0.f ? -1.f : 0.f);
}
__device__ __forceinline__ int imin(int a, int b) { return a < b ? a : b; }
__device__ __forceinline__ int imax(int a, int b) { return a > b ? a : b; }

// Build CSR offsets: qstart[q] = first edge index with key >= q,
// key(e) = valid ? edge_q[e] : N_PTS (padding at end). edge_q is sorted.
__global__ __launch_bounds__(256) void build_qstart_kernel(
    const int* __restrict__ eq, const float* __restrict__ ev,
    int stride, int* __restrict__ qstart)
{
    int e = blockIdx.x * 256 + threadIdx.x;
    if (e >= E_PAD) return;
    int k = (ev[e] > 0.f) ? eq[e * stride] : N_PTS;
    if (k > N_PTS) k = N_PTS;
    int kp = -1;
    if (e > 0) {
        kp = (ev[e - 1] > 0.f) ? eq[(e - 1) * stride] : N_PTS;
        if (kp > N_PTS) kp = N_PTS;
    }
    for (int q = kp + 1; q <= k; ++q) qstart[q] = e;
    if (e == E_PAD - 1) {
        for (int q = k + 1; q <= N_PTS; ++q) qstart[q] = E_PAD;
    }
}

__global__ __launch_bounds__(256) void conv_dense_kernel(
    const float* __restrict__ feats, const float* __restrict__ pos,
    const float* __restrict__ Wconv, const float* __restrict__ Wd,
    const float* __restrict__ bd,
    const int* __restrict__ en, const float* __restrict__ ev,
    const int* __restrict__ qstart, int strideN,
    float* __restrict__ out)
{
    __shared__ float Z[QB][KF][CIN];          // 64 KB
    __shared__ float partial[4][QB][COUT];    // 8 KB

    const int t    = threadIdx.x;
    const int wave = t >> 6;
    const int lane = t & 63;
    const int q0   = blockIdx.x * QB;

    // zero Z
    float* zf = &Z[0][0][0];
    for (int j = t; j < QB * KF * CIN; j += 256) zf[j] = 0.f;
    __syncthreads();

    // ---- Phase 1: edge scatter. Each wave owns QB/4 = 2 queries (private
    // Z slices, wave-lockstep edge loop -> no atomics needed).
    const int ci    = lane & 31;    // channel
    const int dbase = lane >> 5;    // 0 or 1; lane covers d = dbase + 2*dd
    for (int s = 0; s < QB / 4; ++s) {
        const int qs = wave * (QB / 4) + s;
        const int q  = q0 + qs;
        const float qpx = pos[q * 3 + 0];
        const float qpy = pos[q * 3 + 1];
        const float qpz = pos[q * 3 + 2];
        const int lo = qstart[q], hi = qstart[q + 1];
        for (int e = lo; e < hi; ++e) {
            const int   n     = en[e * strideN];
            const float valid = ev[e];
            const float rx = (pos[n * 3 + 0] - qpx) * 20.f;
            const float ry = (pos[n * 3 + 1] - qpy) * 20.f;
            const float rz = (pos[n * 3 + 2] - qpz) * 20.f;
            // ball_to_cube_volume_preserving (match reference op-for-op, f32)
            const float sq   = rx * rx + ry * ry + rz * rz;
            const float nrm  = sqrtf(fmaxf(sq, EPS));
            const float rxy2 = rx * rx + ry * ry;
            const bool  top  = (1.25f * rz * rz > rxy2);
            const float s_top  = sqrtf(fmaxf(3.f * nrm / (nrm + fabsf(rz) + EPS), EPS));
            const float s_side = nrm / sqrtf(fmaxf(rxy2, EPS));
            float cx = top ? rx * s_top : rx * s_side;
            float cy = top ? ry * s_top : ry * s_side;
            float cz = top ? sgnf(rz) * nrm : 1.5f * rz;
            if (sq < EPS) { cx = 0.f; cy = 0.f; cz = 0.f; }
            const float rc2 = cx * cx + cy * cy;
            const float rxy = sqrtf(fmaxf(rc2, EPS));
            const bool  xbig = fabsf(cy) <= fabsf(cx);
            const float safe_x = (fabsf(cx) > EPS) ? cx : 1.f;
            const float safe_y = (fabsf(cy) > EPS) ? cy : 1.f;
            const float qxv = sgnf(cx) * rxy;
            const float qyv = sgnf(cy) * rxy;
            float bx = xbig ? qxv : qyv * FOUR_OVER_PI * atanf(cx / safe_y);
            float by = xbig ? qxv * FOUR_OVER_PI * atanf(cy / safe_x) : qyv;
            if (rc2 < EPS) { bx = 0.f; by = 0.f; }
            // trilinear cell + fractions
            const float ux = fminf(fmaxf((bx + 1.f) * 0.5f * 3.f, 0.f), 3.f);
            const float uy = fminf(fmaxf((by + 1.f) * 0.5f * 3.f, 0.f), 3.f);
            const float uz = fminf(fmaxf((cz + 1.f) * 0.5f * 3.f, 0.f), 3.f);
            const int ix = imin(imax((int)floorf(ux), 0), 2);
            const int iy = imin(imax((int)floorf(uy), 0), 2);
            const int iz = imin(imax((int)floorf(uz), 0), 2);
            const float fx = ux - (float)ix;
            const float fy = uy - (float)iy;
            const float fz = uz - (float)iz;
            const float fjv = feats[n * CIN + ci] * valid;
            #pragma unroll
            for (int dd = 0; dd < 4; ++dd) {
                const int d  = dbase + dd * 2;
                const int dz = (d >> 2) & 1, dy = (d >> 1) & 1, dx = d & 1;
                const float w = (dz ? fz : 1.f - fz) * (dy ? fy : 1.f - fy) *
                                (dx ? fx : 1.f - fx);
                const int idx = ((iz + dz) * KK + (iy + dy)) * KK + (ix + dx);
                Z[qs][idx][ci] += fjv * w;
            }
        }
    }
    __syncthreads();

    // ---- Phase 2: out[q][o] = sum_{kf,i} Z[q][kf][i] * Wconv[kf][i][o]
    // Wave w handles kf in [w*16, w*16+16); lane = o. Each W element loaded
    // once per block, reused for all QB queries.
    float acc[QB];
    #pragma unroll
    for (int qs = 0; qs < QB; ++qs) acc[qs] = 0.f;
    const int o = lane;
    for (int kk = 0; kk < KF / 4; ++kk) {
        const int kf = wave * (KF / 4) + kk;
        #pragma unroll
        for (int ii = 0; ii < CIN; ii += 4) {
            float4 z4[QB];
            #pragma unroll
            for (int qs = 0; qs < QB; ++qs)
                z4[qs] = *(const float4*)&Z[qs][kf][ii];   // LDS broadcast
            #pragma unroll
            for (int c = 0; c < 4; ++c) {
                const float wv = Wconv[(kf * CIN + ii + c) * COUT + o];
                #pragma unroll
                for (int qs = 0; qs < QB; ++qs)
                    acc[qs] += wv * ((const float*)&z4[qs])[c];
            }
        }
    }
    #pragma unroll
    for (int qs = 0; qs < QB; ++qs) partial[wave][qs][o] = acc[qs];
    __syncthreads();

    // ---- Reduce partials + dense head
    for (int s = 0; s < QB / 4; ++s) {
        const int qs = wave * (QB / 4) + s;
        const int q  = q0 + qs;
        const float r = partial[0][qs][o] + partial[1][qs][o] +
                        partial[2][qs][o] + partial[3][qs][o];
        out[q * COUT + o] = r;
        float dacc = bd[o];
        #pragma unroll
        for (int ii = 0; ii < CIN; ++ii)
            dacc += feats[q * CIN + ii] * Wd[ii * COUT + o];
        out[N_PTS * COUT + q * COUT + o] = dacc;
    }
}

extern "C" void kernel_launch(void* const* d_in, const int* in_sizes, int n_in,
                              void* d_out, int out_size, void* d_ws, size_t ws_size,
                              hipStream_t stream)
{
    const float* feats = (const float*)d_in[0];
    const float* pos   = (const float*)d_in[1];
    const float* Wconv = (const float*)d_in[2];
    const float* Wd    = (const float*)d_in[3];
    const float* bd    = (const float*)d_in[4];
    const int*   eq    = (const int*)d_in[5];
    const int*   en    = (const int*)d_in[6];
    const float* ev    = (const float*)d_in[7];
    // int32 vs int64 hedge: element count tells us the stride (little-endian,
    // values < 2^31 so reading the low word is correct either way).
    const int strideQ = in_sizes[5] / E_PAD;
    const int strideN = in_sizes[6] / E_PAD;

    int* qstart = (int*)d_ws;   // (N_PTS+1) ints, rebuilt every call

    build_qstart_kernel<<<E_PAD / 256, 256, 0, stream>>>(eq, ev, strideQ, qstart);
    conv_dense_kernel<<<N_PTS / QB, 256, 0, stream>>>(
        feats, pos, Wconv, Wd, bd, en, ev, qstart, strideN, (float*)d_out);
}

// Round 2
// 252.276 us; speedup vs baseline: 1.3063x; 1.3063x over previous
//
#include <hip/hip_runtime.h>

#define N_PTS 20000
#define CIN   32
#define COUT  64
#define KK    4
#define KF    64            // 4*4*4
#define E_PAD 262144
#define EPS   1e-12f
#define FOUR_OVER_PI 1.27323954473516f
#define QB    8             // queries per block
#define ECH   256           // edge records per chunk

__device__ __forceinline__ float sgnf(float v) {
    return v > 0.f ? 1.f : (v < 0.f ? -1.f : 0.f);
}
__device__ __forceinline__ int imin(int a, int b) { return a < b ? a : b; }
__device__ __forceinline__ int imax(int a, int b) { return a > b ? a : b; }

// Build CSR offsets: qstart[q] = first edge index with key >= q,
// key(e) = valid ? edge_q[e] : N_PTS (padding at end). edge_q is sorted.
__global__ __launch_bounds__(256) void build_qstart_kernel(
    const int* __restrict__ eq, const float* __restrict__ ev,
    int stride, int* __restrict__ qstart)
{
    int e = blockIdx.x * 256 + threadIdx.x;
    if (e >= E_PAD) return;
    int k = (ev[e] > 0.f) ? eq[e * stride] : N_PTS;
    if (k > N_PTS) k = N_PTS;
    int kp = -1;
    if (e > 0) {
        kp = (ev[e - 1] > 0.f) ? eq[(e - 1) * stride] : N_PTS;
        if (kp > N_PTS) kp = N_PTS;
    }
    for (int q = kp + 1; q <= k; ++q) qstart[q] = e;
    if (e == E_PAD - 1) {
        for (int q = k + 1; q <= N_PTS; ++q) qstart[q] = E_PAD;
    }
}

__global__ __launch_bounds__(256) void conv_dense_kernel(
    const float* __restrict__ feats, const float* __restrict__ pos,
    const float* __restrict__ Wconv, const float* __restrict__ Wd,
    const float* __restrict__ bd,
    const int* __restrict__ en, const float* __restrict__ ev,
    const int* __restrict__ qstart, int strideN,
    float* __restrict__ out)
{
    __shared__ float Z[QB][KF][CIN];          // 64 KB
    __shared__ float partial[4][QB][COUT];    // 8 KB
    __shared__ int   rec_n[ECH];              // 1 KB
    __shared__ int   rec_b[ECH];              // 1 KB
    __shared__ float rec_fx[ECH], rec_fy[ECH], rec_fz[ECH];  // 3 KB
    __shared__ int   qs9[QB + 1];

    const int t    = threadIdx.x;
    const int wave = t >> 6;
    const int lane = t & 63;
    const int q0   = blockIdx.x * QB;

    if (t <= QB) qs9[t] = qstart[q0 + t];
    // zero Z
    float* zf = &Z[0][0][0];
    for (int j = t; j < QB * KF * CIN; j += 256) zf[j] = 0.f;
    __syncthreads();

    const int eLo = qs9[0], eHi = qs9[QB];

    const int ci    = lane & 31;    // channel
    const int dbase = lane >> 5;    // dx parity this half-wave owns

    for (int cb = eLo; cb < eHi; cb += ECH) {
        const int cnt = imin(ECH, eHi - cb);

        // ---- Geometry pass: one thread per edge, computed ONCE.
        if (t < cnt) {
            const int e = cb + t;
            int q = q0;
            #pragma unroll
            for (int s = 1; s < QB; ++s) if (e >= qs9[s]) q = q0 + s;
            const int n = en[e * strideN];
            const float rx = (pos[n * 3 + 0] - pos[q * 3 + 0]) * 20.f;
            const float ry = (pos[n * 3 + 1] - pos[q * 3 + 1]) * 20.f;
            const float rz = (pos[n * 3 + 2] - pos[q * 3 + 2]) * 20.f;
            const float sq   = rx * rx + ry * ry + rz * rz;
            const float nrm  = sqrtf(fmaxf(sq, EPS));
            const float rxy2 = rx * rx + ry * ry;
            const bool  top  = (1.25f * rz * rz > rxy2);
            const float s_top  = sqrtf(fmaxf(3.f * nrm / (nrm + fabsf(rz) + EPS), EPS));
            const float s_side = nrm / sqrtf(fmaxf(rxy2, EPS));
            float cx = top ? rx * s_top : rx * s_side;
            float cy = top ? ry * s_top : ry * s_side;
            float cz = top ? sgnf(rz) * nrm : 1.5f * rz;
            if (sq < EPS) { cx = 0.f; cy = 0.f; cz = 0.f; }
            const float rc2 = cx * cx + cy * cy;
            const float rxy = sqrtf(fmaxf(rc2, EPS));
            const bool  xbig = fabsf(cy) <= fabsf(cx);
            const float safe_x = (fabsf(cx) > EPS) ? cx : 1.f;
            const float safe_y = (fabsf(cy) > EPS) ? cy : 1.f;
            const float qxv = sgnf(cx) * rxy;
            const float qyv = sgnf(cy) * rxy;
            float bx = xbig ? qxv : qyv * FOUR_OVER_PI * atanf(cx / safe_y);
            float by = xbig ? qxv * FOUR_OVER_PI * atanf(cy / safe_x) : qyv;
            if (rc2 < EPS) { bx = 0.f; by = 0.f; }
            const float ux = fminf(fmaxf((bx + 1.f) * 0.5f * 3.f, 0.f), 3.f);
            const float uy = fminf(fmaxf((by + 1.f) * 0.5f * 3.f, 0.f), 3.f);
            const float uz = fminf(fmaxf((cz + 1.f) * 0.5f * 3.f, 0.f), 3.f);
            const int ix = imin(imax((int)floorf(ux), 0), 2);
            const int iy = imin(imax((int)floorf(uy), 0), 2);
            const int iz = imin(imax((int)floorf(uz), 0), 2);
            rec_n[t]  = n;
            rec_b[t]  = (iz * KK + iy) * KK + ix;
            rec_fx[t] = ux - (float)ix;
            rec_fy[t] = uy - (float)iy;
            rec_fz[t] = uz - (float)iz;
        }
        __syncthreads();

        // ---- Accumulation pass: wave owns 2 queries; light per-edge body.
        for (int s = 0; s < QB / 4; ++s) {
            const int qs = wave * (QB / 4) + s;
            const int lo = imax(qs9[qs], cb);
            const int hi = imin(qs9[qs + 1], cb + cnt);
            for (int e = lo; e < hi; ++e) {
                const int r  = e - cb;
                const int n  = rec_n[r];
                const int ib = rec_b[r];
                const float fx = rec_fx[r];
                const float fy = rec_fy[r];
                const float fz = rec_fz[r];
                const float fj  = feats[n * CIN + ci];
                const float wxf = dbase ? fx : 1.f - fx;
                #pragma unroll
                for (int dd = 0; dd < 4; ++dd) {
                    const int dy = dd & 1, dz = dd >> 1;
                    const float w = (dz ? fz : 1.f - fz) * (dy ? fy : 1.f - fy) * wxf;
                    Z[qs][ib + dz * 16 + dy * 4 + dbase][ci] += fj * w;
                }
            }
        }
        __syncthreads();
    }

    // ---- Phase 2: out[q][o] = sum_{kf,i} Z[q][kf][i] * Wconv[kf][i][o]
    // Wave w handles kf in [w*16, w*16+16); lane = o. Each W element loaded
    // once per block, reused for all QB queries.
    float acc[QB];
    #pragma unroll
    for (int qs = 0; qs < QB; ++qs) acc[qs] = 0.f;
    const int o = lane;
    for (int kk = 0; kk < KF / 4; ++kk) {
        const int kf = wave * (KF / 4) + kk;
        #pragma unroll
        for (int ii = 0; ii < CIN; ii += 4) {
            float4 z4[QB];
            #pragma unroll
            for (int qs = 0; qs < QB; ++qs)
                z4[qs] = *(const float4*)&Z[qs][kf][ii];   // LDS broadcast
            #pragma unroll
            for (int c = 0; c < 4; ++c) {
                const float wv = Wconv[(kf * CIN + ii + c) * COUT + o];
                #pragma unroll
                for (int qs = 0; qs < QB; ++qs)
                    acc[qs] += wv * ((const float*)&z4[qs])[c];
            }
        }
    }
    #pragma unroll
    for (int qs = 0; qs < QB; ++qs) partial[wave][qs][o] = acc[qs];
    __syncthreads();

    // ---- Reduce partials + dense head
    for (int s = 0; s < QB / 4; ++s) {
        const int qs = wave * (QB / 4) + s;
        const int q  = q0 + qs;
        const float r = partial[0][qs][o] + partial[1][qs][o] +
                        partial[2][qs][o] + partial[3][qs][o];
        out[q * COUT + o] = r;
        float dacc = bd[o];
        #pragma unroll
        for (int ii = 0; ii < CIN; ++ii)
            dacc += feats[q * CIN + ii] * Wd[ii * COUT + o];
        out[N_PTS * COUT + q * COUT + o] = dacc;
    }
}

extern "C" void kernel_launch(void* const* d_in, const int* in_sizes, int n_in,
                              void* d_out, int out_size, void* d_ws, size_t ws_size,
                              hipStream_t stream)
{
    const float* feats = (const float*)d_in[0];
    const float* pos   = (const float*)d_in[1];
    const float* Wconv = (const float*)d_in[2];
    const float* Wd    = (const float*)d_in[3];
    const float* bd    = (const float*)d_in[4];
    const int*   eq    = (const int*)d_in[5];
    const int*   en    = (const int*)d_in[6];
    const float* ev    = (const float*)d_in[7];
    // int32 vs int64 hedge: element count tells us the stride (little-endian,
    // values < 2^31 so reading the low word is correct either way).
    const int strideQ = in_sizes[5] / E_PAD;
    const int strideN = in_sizes[6] / E_PAD;

    int* qstart = (int*)d_ws;   // (N_PTS+1) ints, rebuilt every call

    build_qstart_kernel<<<E_PAD / 256, 256, 0, stream>>>(eq, ev, strideQ, qstart);
    conv_dense_kernel<<<N_PTS / QB, 256, 0, stream>>>(
        feats, pos, Wconv, Wd, bd, en, ev, qstart, strideN, (float*)d_out);
}

// Round 3
// 91.778 us; speedup vs baseline: 3.5908x; 2.7488x over previous
//
#include <hip/hip_runtime.h>

#define N_PTS 20000
#define CIN   32
#define COUT  64
#define KK    4
#define KF    64
#define KDIM  2048          // KF*CIN
#define E_PAD 262144
#define EPS   1e-12f
#define FOUR_OVER_PI 1.27323954473516f
#define QB    8             // queries per block (scatter)
#define ECH   512           // edge records per chunk
#define MT    32            // M-tile (gemm)

typedef __attribute__((ext_vector_type(8))) short bf16x8;
typedef __attribute__((ext_vector_type(4))) float f32x4;

__device__ __forceinline__ float sgnf(float v) {
    return v > 0.f ? 1.f : (v < 0.f ? -1.f : 0.f);
}
__device__ __forceinline__ int imin(int a, int b) { return a < b ? a : b; }
__device__ __forceinline__ int imax(int a, int b) { return a > b ? a : b; }

__device__ __forceinline__ unsigned short f2bf(float f) {   // RNE f32->bf16
    unsigned u = __float_as_uint(f);
    u = u + 0x7fffu + ((u >> 16) & 1u);
    return (unsigned short)(u >> 16);
}

// Shared geometry: ball_to_cube_volume_preserving + trilinear cell (f32,
// op-for-op vs reference).
__device__ __forceinline__ void edge_geom(
    const float* __restrict__ pos, int n, int q,
    int& cellb, float& ofx, float& ofy, float& ofz)
{
    const float rx = (pos[n * 3 + 0] - pos[q * 3 + 0]) * 20.f;
    const float ry = (pos[n * 3 + 1] - pos[q * 3 + 1]) * 20.f;
    const float rz = (pos[n * 3 + 2] - pos[q * 3 + 2]) * 20.f;
    const float sq   = rx * rx + ry * ry + rz * rz;
    const float nrm  = sqrtf(fmaxf(sq, EPS));
    const float rxy2 = rx * rx + ry * ry;
    const bool  top  = (1.25f * rz * rz > rxy2);
    const float s_top  = sqrtf(fmaxf(3.f * nrm / (nrm + fabsf(rz) + EPS), EPS));
    const float s_side = nrm / sqrtf(fmaxf(rxy2, EPS));
    float cx = top ? rx * s_top : rx * s_side;
    float cy = top ? ry * s_top : ry * s_side;
    float cz = top ? sgnf(rz) * nrm : 1.5f * rz;
    if (sq < EPS) { cx = 0.f; cy = 0.f; cz = 0.f; }
    const float rc2 = cx * cx + cy * cy;
    const float rxy = sqrtf(fmaxf(rc2, EPS));
    const bool  xbig = fabsf(cy) <= fabsf(cx);
    const float safe_x = (fabsf(cx) > EPS) ? cx : 1.f;
    const float safe_y = (fabsf(cy) > EPS) ? cy : 1.f;
    const float qxv = sgnf(cx) * rxy;
    const float qyv = sgnf(cy) * rxy;
    float bx = xbig ? qxv : qyv * FOUR_OVER_PI * atanf(cx / safe_y);
    float by = xbig ? qxv * FOUR_OVER_PI * atanf(cy / safe_x) : qyv;
    if (rc2 < EPS) { bx = 0.f; by = 0.f; }
    const float ux = fminf(fmaxf((bx + 1.f) * 0.5f * 3.f, 0.f), 3.f);
    const float uy = fminf(fmaxf((by + 1.f) * 0.5f * 3.f, 0.f), 3.f);
    const float uz = fminf(fmaxf((cz + 1.f) * 0.5f * 3.f, 0.f), 3.f);
    const int ix = imin(imax((int)floorf(ux), 0), 2);
    const int iy = imin(imax((int)floorf(uy), 0), 2);
    const int iz = imin(imax((int)floorf(uz), 0), 2);
    cellb = (iz * KK + iy) * KK + ix;
    ofx = ux - (float)ix; ofy = uy - (float)iy; ofz = uz - (float)iz;
}

// CSR offsets from sorted edge_q (padding keyed to N_PTS).
__global__ __launch_bounds__(256) void build_qstart_kernel(
    const int* __restrict__ eq, const float* __restrict__ ev,
    int stride, int* __restrict__ qstart)
{
    int e = blockIdx.x * 256 + threadIdx.x;
    if (e >= E_PAD) return;
    int k = (ev[e] > 0.f) ? eq[e * stride] : N_PTS;
    if (k > N_PTS) k = N_PTS;
    int kp = -1;
    if (e > 0) {
        kp = (ev[e - 1] > 0.f) ? eq[(e - 1) * stride] : N_PTS;
        if (kp > N_PTS) kp = N_PTS;
    }
    for (int q = kp + 1; q <= k; ++q) qstart[q] = e;
    if (e == E_PAD - 1) {
        for (int q = k + 1; q <= N_PTS; ++q) qstart[q] = E_PAD;
    }
}

// W[2048][64] f32 -> bf16 in B-fragment order: Wfrag[ks][nf][lane][j].
__global__ __launch_bounds__(256) void reorder_w_kernel(
    const float* __restrict__ Wconv, unsigned short* __restrict__ Wfrag)
{
    const int idx = blockIdx.x * 256 + threadIdx.x;   // 131072 total
    const int j    = idx & 7;
    const int lane = (idx >> 3) & 63;
    const int nf   = (idx >> 9) & 3;
    const int ks   = idx >> 11;
    const int k    = ks * 32 + ((lane >> 4) << 3) + j;
    const int col  = nf * 16 + (lane & 15);
    Wfrag[idx] = f2bf(Wconv[k * COUT + col]);
}

// Scatter: 8 waves, 1 query per wave. Geometry computed once per edge,
// Z accumulated in f32 LDS, written out as bf16 rows of the global Z.
__global__ __launch_bounds__(512) void scatter_kernel(
    const float* __restrict__ feats, const float* __restrict__ pos,
    const int* __restrict__ en, const int strideN,
    const int* __restrict__ qstart, unsigned short* __restrict__ Zb)
{
    __shared__ float Z[QB][KF][CIN];                         // 64 KB
    __shared__ int   rec_n[ECH], rec_b[ECH];                 // 4 KB
    __shared__ float rec_fx[ECH], rec_fy[ECH], rec_fz[ECH];  // 6 KB
    __shared__ int   qs9[QB + 1];

    const int t    = threadIdx.x;
    const int wave = t >> 6;
    const int lane = t & 63;
    const int q0   = blockIdx.x * QB;

    if (t <= QB) qs9[t] = qstart[q0 + t];
    float* zf = &Z[0][0][0];
    for (int j = t; j < QB * KDIM; j += 512) zf[j] = 0.f;
    __syncthreads();

    const int eLo = qs9[0], eHi = qs9[QB];
    const int ci    = lane & 31;
    const int dbase = lane >> 5;

    for (int cb = eLo; cb < eHi; cb += ECH) {
        const int cnt = imin(ECH, eHi - cb);
        if (t < cnt) {
            const int e = cb + t;
            int q = q0;
            #pragma unroll
            for (int s = 1; s < QB; ++s) if (e >= qs9[s]) q = q0 + s;
            const int n = en[e * strideN];
            int ib; float fx, fy, fz;
            edge_geom(pos, n, q, ib, fx, fy, fz);
            rec_n[t] = n; rec_b[t] = ib;
            rec_fx[t] = fx; rec_fy[t] = fy; rec_fz[t] = fz;
        }
        __syncthreads();

        const int lo = imax(qs9[wave], cb);
        const int hi = imin(qs9[wave + 1], cb + cnt);
        for (int e = lo; e < hi; ++e) {
            const int r  = e - cb;
            const int n  = rec_n[r];
            const int ib = rec_b[r];
            const float fx = rec_fx[r], fy = rec_fy[r], fz = rec_fz[r];
            const float fj  = feats[n * CIN + ci];
            const float wxf = dbase ? fx : 1.f - fx;
            #pragma unroll
            for (int dd = 0; dd < 4; ++dd) {
                const int dy = dd & 1, dz = dd >> 1;
                const float w = (dz ? fz : 1.f - fz) * (dy ? fy : 1.f - fy) * wxf;
                Z[wave][ib + dz * 16 + dy * 4 + dbase][ci] += fj * w;
            }
        }
        __syncthreads();
    }

    // f32 LDS -> bf16 global rows [q0 .. q0+7] (contiguous), packed pairs.
    unsigned* zo = (unsigned*)(Zb + (size_t)q0 * KDIM);
    for (int p = t; p < QB * KDIM / 2; p += 512) {
        zo[p] = (unsigned)f2bf(zf[2 * p]) | ((unsigned)f2bf(zf[2 * p + 1]) << 16);
    }
}

// GEMM: out[20000][64] = Zb[20000][2048] x W[2048][64] (bf16 MFMA, f32 acc),
// plus the dense head in the epilogue. 4 waves split K; LDS reduce.
__global__ __launch_bounds__(256) void gemm_kernel(
    const unsigned short* __restrict__ Zb, const unsigned short* __restrict__ Wfrag,
    const float* __restrict__ feats, const float* __restrict__ Wd,
    const float* __restrict__ bd, float* __restrict__ out)
{
    __shared__ float red[4][MT][COUT + 2];   // padded to dodge bank conflicts

    const int t    = threadIdx.x;
    const int wave = t >> 6;
    const int lane = t & 63;
    const int m0   = blockIdx.x * MT;
    const int r16  = lane & 15;
    const int kgrp = lane >> 4;

    f32x4 acc[2][4];
    #pragma unroll
    for (int mi = 0; mi < 2; ++mi)
        #pragma unroll
        for (int nf = 0; nf < 4; ++nf)
            acc[mi][nf] = (f32x4){0.f, 0.f, 0.f, 0.f};

    for (int ks16 = 0; ks16 < 16; ++ks16) {
        const int ks   = wave * 16 + ks16;        // global k-step (32 wide)
        const int koff = ks * 32 + kgrp * 8;
        bf16x8 af[2], bfg[4];
        #pragma unroll
        for (int mi = 0; mi < 2; ++mi)
            af[mi] = *(const bf16x8*)(Zb + (size_t)(m0 + mi * 16 + r16) * KDIM + koff);
        #pragma unroll
        for (int nf = 0; nf < 4; ++nf)
            bfg[nf] = *(const bf16x8*)(Wfrag + (((ks * 4 + nf) * 64) + lane) * 8);
        #pragma unroll
        for (int mi = 0; mi < 2; ++mi)
            #pragma unroll
            for (int nf = 0; nf < 4; ++nf)
                acc[mi][nf] = __builtin_amdgcn_mfma_f32_16x16x32_bf16(
                    af[mi], bfg[nf], acc[mi][nf], 0, 0, 0);
    }

    #pragma unroll
    for (int mi = 0; mi < 2; ++mi)
        #pragma unroll
        for (int nf = 0; nf < 4; ++nf)
            #pragma unroll
            for (int rg = 0; rg < 4; ++rg)
                red[wave][mi * 16 + kgrp * 4 + rg][nf * 16 + r16] = acc[mi][nf][rg];
    __syncthreads();

    for (int idx = t; idx < MT * COUT; idx += 256) {
        const int r = idx >> 6, o = idx & 63;
        const int q = m0 + r;
        out[q * COUT + o] =
            red[0][r][o] + red[1][r][o] + red[2][r][o] + red[3][r][o];
        float dacc = bd[o];
        #pragma unroll
        for (int i = 0; i < CIN; ++i)
            dacc += feats[q * CIN + i] * Wd[i * COUT + o];
        out[N_PTS * COUT + q * COUT + o] = dacc;
    }
}

// ---------------- Fallback (round-2 monolithic) if ws too small ----------
__global__ __launch_bounds__(256) void conv_dense_kernel(
    const float* __restrict__ feats, const float* __restrict__ pos,
    const float* __restrict__ Wconv, const float* __restrict__ Wd,
    const float* __restrict__ bd,
    const int* __restrict__ en, const float* __restrict__ ev,
    const int* __restrict__ qstart, int strideN,
    float* __restrict__ out)
{
    __shared__ float Z[QB][KF][CIN];
    __shared__ float partial[4][QB][COUT];
    __shared__ int   rec_n[256], rec_b[256];
    __shared__ float rec_fx[256], rec_fy[256], rec_fz[256];
    __shared__ int   qs9[QB + 1];

    const int t = threadIdx.x, wave = t >> 6, lane = t & 63;
    const int q0 = blockIdx.x * QB;
    if (t <= QB) qs9[t] = qstart[q0 + t];
    float* zf = &Z[0][0][0];
    for (int j = t; j < QB * KF * CIN; j += 256) zf[j] = 0.f;
    __syncthreads();
    const int eLo = qs9[0], eHi = qs9[QB];
    const int ci = lane & 31, dbase = lane >> 5;
    for (int cb = eLo; cb < eHi; cb += 256) {
        const int cnt = imin(256, eHi - cb);
        if (t < cnt) {
            const int e = cb + t;
            int q = q0;
            #pragma unroll
            for (int s = 1; s < QB; ++s) if (e >= qs9[s]) q = q0 + s;
            const int n = en[e * strideN];
            int ib; float fx, fy, fz;
            edge_geom(pos, n, q, ib, fx, fy, fz);
            rec_n[t] = n; rec_b[t] = ib;
            rec_fx[t] = fx; rec_fy[t] = fy; rec_fz[t] = fz;
        }
        __syncthreads();
        for (int s = 0; s < QB / 4; ++s) {
            const int qs = wave * (QB / 4) + s;
            const int lo = imax(qs9[qs], cb);
            const int hi = imin(qs9[qs + 1], cb + cnt);
            for (int e = lo; e < hi; ++e) {
                const int r = e - cb;
                const int n = rec_n[r], ib = rec_b[r];
                const float fx = rec_fx[r], fy = rec_fy[r], fz = rec_fz[r];
                const float fj = feats[n * CIN + ci];
                const float wxf = dbase ? fx : 1.f - fx;
                #pragma unroll
                for (int dd = 0; dd < 4; ++dd) {
                    const int dy = dd & 1, dz = dd >> 1;
                    const float w = (dz ? fz : 1.f - fz) * (dy ? fy : 1.f - fy) * wxf;
                    Z[qs][ib + dz * 16 + dy * 4 + dbase][ci] += fj * w;
                }
            }
        }
        __syncthreads();
    }
    float acc[QB];
    #pragma unroll
    for (int qs = 0; qs < QB; ++qs) acc[qs] = 0.f;
    const int o = lane;
    for (int kk = 0; kk < KF / 4; ++kk) {
        const int kf = wave * (KF / 4) + kk;
        #pragma unroll
        for (int ii = 0; ii < CIN; ii += 4) {
            float4 z4[QB];
            #pragma unroll
            for (int qs = 0; qs < QB; ++qs)
                z4[qs] = *(const float4*)&Z[qs][kf][ii];
            #pragma unroll
            for (int c = 0; c < 4; ++c) {
                const float wv = Wconv[(kf * CIN + ii + c) * COUT + o];
                #pragma unroll
                for (int qs = 0; qs < QB; ++qs)
                    acc[qs] += wv * ((const float*)&z4[qs])[c];
            }
        }
    }
    #pragma unroll
    for (int qs = 0; qs < QB; ++qs) partial[wave][qs][o] = acc[qs];
    __syncthreads();
    for (int s = 0; s < QB / 4; ++s) {
        const int qs = wave * (QB / 4) + s;
        const int q  = q0 + qs;
        out[q * COUT + o] = partial[0][qs][o] + partial[1][qs][o] +
                            partial[2][qs][o] + partial[3][qs][o];
        float dacc = bd[o];
        #pragma unroll
        for (int ii = 0; ii < CIN; ++ii)
            dacc += feats[q * CIN + ii] * Wd[ii * COUT + o];
        out[N_PTS * COUT + q * COUT + o] = dacc;
    }
}

extern "C" void kernel_launch(void* const* d_in, const int* in_sizes, int n_in,
                              void* d_out, int out_size, void* d_ws, size_t ws_size,
                              hipStream_t stream)
{
    const float* feats = (const float*)d_in[0];
    const float* pos   = (const float*)d_in[1];
    const float* Wconv = (const float*)d_in[2];
    const float* Wd    = (const float*)d_in[3];
    const float* bd    = (const float*)d_in[4];
    const int*   eq    = (const int*)d_in[5];
    const int*   en    = (const int*)d_in[6];
    const float* ev    = (const float*)d_in[7];
    const int strideQ = in_sizes[5] / E_PAD;   // int32 vs int64 hedge
    const int strideN = in_sizes[6] / E_PAD;

    int* qstart = (int*)d_ws;
    const size_t offW = 81920;                       // after qstart (80 KB)
    const size_t offZ = offW + 262144;               // after Wfrag (256 KB)
    const size_t needed = offZ + (size_t)N_PTS * KDIM * 2;

    build_qstart_kernel<<<E_PAD / 256, 256, 0, stream>>>(eq, ev, strideQ, qstart);

    if (ws_size >= needed) {
        unsigned short* Wfrag = (unsigned short*)((char*)d_ws + offW);
        unsigned short* Zb    = (unsigned short*)((char*)d_ws + offZ);
        reorder_w_kernel<<<KDIM * COUT / 256, 256, 0, stream>>>(Wconv, Wfrag);
        scatter_kernel<<<N_PTS / QB, 512, 0, stream>>>(
            feats, pos, en, strideN, qstart, Zb);
        gemm_kernel<<<N_PTS / MT, 256, 0, stream>>>(
            Zb, Wfrag, feats, Wd, bd, (float*)d_out);
    } else {
        conv_dense_kernel<<<N_PTS / QB, 256, 0, stream>>>(
            feats, pos, Wconv, Wd, bd, en, ev, qstart, strideN, (float*)d_out);
    }
}